// Round 8
// baseline (364.242 us; speedup 1.0000x reference)
//
#include <hip/hip_runtime.h>
#include <hip/hip_bf16.h>
#include <math.h>

typedef unsigned int uint;
typedef unsigned short ushort;
using f32x4 = __attribute__((ext_vector_type(4))) float;
using s16x8 = __attribute__((ext_vector_type(8))) short;

#define NSLOT 64   // replicated BN-stat buffers (de-contend epilogue atomics)

__device__ __forceinline__ float bflo(uint u) { return __uint_as_float(u << 16); }
__device__ __forceinline__ float bfhi(uint u) { return __uint_as_float(u & 0xffff0000u); }
__device__ __forceinline__ ushort f2bf(float f) {
    uint u = __float_as_uint(f);
    return (ushort)((u + 0x7fffu + ((u >> 16) & 1u)) >> 16);   // RNE
}
__device__ __forceinline__ float sel4f(float a, float b, float c, float d, int i) {
    float r = a; r = (i == 1) ? b : r; r = (i == 2) ? c : r; r = (i == 3) ? d : r; return r;
}
__device__ __forceinline__ int sel4i(int a, int b, int c, int d, int i) {
    int r = a; r = (i == 1) ? b : r; r = (i == 2) ? c : r; r = (i == 3) ? d : r; return r;
}

// ---------------- Degree / CSR ----------------

__global__ void deg_count(const int* __restrict__ dst, int* __restrict__ deg, int E) {
    int e = blockIdx.x * 256 + threadIdx.x;
    if (e < E) atomicAdd(&deg[dst[e]], 1);
}

// phase 1: per-block sum of deg
__global__ __launch_bounds__(256) void deg_block_sum(const int* __restrict__ deg,
                                                     int* __restrict__ bsum, int N) {
    __shared__ int s[256];
    int i = blockIdx.x * 256 + threadIdx.x;
    s[threadIdx.x] = (i < N) ? deg[i] : 0;
    __syncthreads();
    #pragma unroll
    for (int off = 128; off > 0; off >>= 1) {
        if (threadIdx.x < off) s[threadIdx.x] += s[threadIdx.x + off];
        __syncthreads();
    }
    if (threadIdx.x == 0) bsum[blockIdx.x] = s[0];
}

// phase 2: every block scans all block-sums in LDS (nblk<=256) + intra-block deg scan
__global__ __launch_bounds__(256) void fill_rowstart(const int* __restrict__ deg,
                                                     const int* __restrict__ bsum,
                                                     int* __restrict__ row_start,
                                                     int* __restrict__ cursor,
                                                     float* __restrict__ dinv,
                                                     int N, int E, int nblk) {
    __shared__ int s[256];
    __shared__ int sb[256];
    int t = threadIdx.x;
    int i = blockIdx.x * 256 + t;
    int dg = (i < N) ? deg[i] : 0;
    s[t] = dg;
    sb[t] = (t < nblk) ? bsum[t] : 0;
    __syncthreads();
    for (int off = 1; off < 256; off <<= 1) {
        int v1 = (t >= off) ? s[t - off] : 0;
        int v2 = (t >= off) ? sb[t - off] : 0;
        __syncthreads();
        s[t] += v1;
        sb[t] += v2;
        __syncthreads();
    }
    if (i < N) {
        int boff = (blockIdx.x == 0) ? 0 : sb[blockIdx.x - 1];
        int excl = boff + s[t] - dg;
        row_start[i] = excl;
        cursor[i] = excl;
        dinv[i] = rsqrtf((float)dg + 1.0f);
    }
    if (i == 0) row_start[N] = E;
}

__global__ void csr_fill(const int* __restrict__ src, const int* __restrict__ dst,
                         const float* __restrict__ dinv, int* __restrict__ cursor,
                         int2* __restrict__ csr2, int E) {
    int e = blockIdx.x * 256 + threadIdx.x;
    if (e >= E) return;
    int s = src[e], d = dst[e];
    int pos = atomicAdd(&cursor[d], 1);
    csr2[pos] = make_int2(s, __float_as_int(dinv[s] * dinv[d]));
}

// ---------------- Weight prep: 3x (W [k][n] f32 -> [n][k] bf16) + w2t ----------------

__global__ __launch_bounds__(256) void prep_weights(const float* __restrict__ W1,
                                                    const float* __restrict__ W2,
                                                    const float* __restrict__ W3,
                                                    const float* __restrict__ l2w,
                                                    ushort* __restrict__ wt1,
                                                    ushort* __restrict__ wt2,
                                                    ushort* __restrict__ wt3,
                                                    float* __restrict__ w2t) {
    int i = blockIdx.x * 256 + threadIdx.x;      // 0..49151
    int li = i & 16383;
    int k = li >> 7, n = li & 127;
    const float* Ws = (i < 16384) ? W1 : (i < 32768) ? W2 : W3;
    ushort* Wd = (i < 16384) ? wt1 : (i < 32768) ? wt2 : wt3;
    Wd[n * 128 + k] = f2bf(Ws[li]);
    if (i < 1280) {
        int kk = i / 10, c = i % 10;
        w2t[c * 128 + kk] = l2w[i];
    }
}

// ---------------- bf16 MFMA GEMM (optionally fused log_softmax head) ----------------

template<bool XF32, bool AFF, bool BIAS, bool RELU, bool HEAD>
__global__ __launch_bounds__(256) void gemm_mfma(const void* __restrict__ Xv,
                                                 const float* __restrict__ scale,
                                                 const float* __restrict__ shift,
                                                 const ushort* __restrict__ Bt,
                                                 const float* __restrict__ bias,
                                                 ushort* __restrict__ Y,
                                                 const float* __restrict__ W2t,
                                                 const float* __restrict__ b2,
                                                 float* __restrict__ OUT, int N) {
    __shared__ char smem[16384 + 32768];
    char* Al = smem;            // 64 rows x 256B, unit u at row*256 + (u^(row&7))*16
    char* Bl = smem + 16384;    // 128 n-rows x 256B, same swizzle

    int tid = threadIdx.x;
    int brow = blockIdx.x * 64;

    {
        int n = tid >> 1, h = tid & 1;
        const uint4* srcp = (const uint4*)(Bt + n * 128 + h * 64);
        #pragma unroll
        for (int i = 0; i < 8; ++i) {
            uint4 v = srcp[i];
            int u = (h * 8 + i) ^ (n & 7);
            *(uint4*)(Bl + n * 256 + u * 16) = v;
        }
    }
    {
        int r = tid >> 2, c0 = (tid & 3) * 32;
        int row = brow + r;
        bool ok = row < N;
        uint pk[16];
        if (XF32) {
            const float* Xr = (const float*)Xv + (size_t)row * 128 + c0;
            #pragma unroll
            for (int i = 0; i < 16; ++i) {
                float f0 = ok ? Xr[i * 2] : 0.f;
                float f1 = ok ? Xr[i * 2 + 1] : 0.f;
                pk[i] = (uint)f2bf(f0) | ((uint)f2bf(f1) << 16);
            }
        } else {
            const uint* Xr = (const uint*)((const ushort*)Xv + (size_t)row * 128 + c0);
            #pragma unroll
            for (int i = 0; i < 16; ++i) {
                uint u = ok ? Xr[i] : 0u;
                float f0 = bflo(u), f1 = bfhi(u);
                if (AFF) {
                    int c = c0 + i * 2;
                    f0 = f0 * scale[c] + shift[c];
                    f1 = f1 * scale[c + 1] + shift[c + 1];
                }
                pk[i] = (uint)f2bf(f0) | ((uint)f2bf(f1) << 16);
            }
        }
        #pragma unroll
        for (int i = 0; i < 4; ++i) {
            int u = ((tid & 3) * 4 + i) ^ (r & 7);
            *(uint4*)(Al + r * 256 + u * 16) = *(uint4*)&pk[i * 4];
        }
    }
    __syncthreads();

    int lane = tid & 63, w = tid >> 6;
    int m = lane & 15, g = lane >> 4;
    int wr = w * 16;

    f32x4 acc[8];
    #pragma unroll
    for (int nt = 0; nt < 8; ++nt) acc[nt] = (f32x4){0.f, 0.f, 0.f, 0.f};

    #pragma unroll
    for (int kk = 0; kk < 4; ++kk) {
        int u = (kk * 4 + g) ^ (m & 7);
        s16x8 a = *(const s16x8*)(Al + (wr + m) * 256 + u * 16);
        #pragma unroll
        for (int nt = 0; nt < 8; ++nt) {
            s16x8 b = *(const s16x8*)(Bl + (nt * 16 + m) * 256 + u * 16);
            acc[nt] = __builtin_amdgcn_mfma_f32_16x16x32_bf16(a, b, acc[nt], 0, 0, 0);
        }
    }

    float bv[8];
    if (BIAS) {
        #pragma unroll
        for (int nt = 0; nt < 8; ++nt) bv[nt] = bias[nt * 16 + m];
    }

    if (!HEAD) {
        #pragma unroll
        for (int i = 0; i < 4; ++i) {
            int row = brow + wr + g * 4 + i;
            if (row < N) {
                #pragma unroll
                for (int nt = 0; nt < 8; ++nt) {
                    float v = acc[nt][i];
                    if (BIAS) v += bv[nt];
                    if (RELU) v = fmaxf(v, 0.f);
                    Y[(size_t)row * 128 + nt * 16 + m] = f2bf(v);
                }
            }
        }
    } else {
        // fused MLP head: stash f32 h rows in LDS, then log_softmax of 10 logits per row
        float* hl = (float*)smem;   // [64][132] f32 = 33792 B (tile staging is done)
        __syncthreads();            // all waves finished reading Al/Bl
        #pragma unroll
        for (int i = 0; i < 4; ++i) {
            int r = wr + g * 4 + i;
            #pragma unroll
            for (int nt = 0; nt < 8; ++nt) {
                float v = acc[nt][i];
                if (BIAS) v += bv[nt];
                if (RELU) v = fmaxf(v, 0.f);
                hl[r * 132 + nt * 16 + m] = v;
            }
        }
        __syncthreads();
        for (int r = 0; r < 16; ++r) {
            int grow = brow + wr + r;
            float2 h2 = *(const float2*)&hl[(wr + r) * 132 + lane * 2];
            float logit[10];
            #pragma unroll
            for (int c = 0; c < 10; ++c) {
                float2 wv = *(const float2*)&W2t[c * 128 + lane * 2];
                float p = h2.x * wv.x + h2.y * wv.y;
                #pragma unroll
                for (int off = 32; off > 0; off >>= 1) p += __shfl_xor(p, off, 64);
                logit[c] = p + b2[c];
            }
            float mx = logit[0];
            #pragma unroll
            for (int c = 1; c < 10; ++c) mx = fmaxf(mx, logit[c]);
            float sum = 0.f;
            #pragma unroll
            for (int c = 0; c < 10; ++c) sum += expf(logit[c] - mx);
            float lse = mx + logf(sum);
            if (lane < 10 && grow < N) OUT[(size_t)grow * 10 + lane] = logit[lane] - lse;
        }
    }
}

// ---------------- Chunked segmented gather + self-loop + bias + ReLU + BN stats ----------------
// One wave per 4-node chunk (contiguous CSR edges). 16-deep load pipeline.
// BN stats: per-block LDS reduce -> atomics into one of NSLOT replicated buffers.

__global__ __launch_bounds__(256) void gather_fused(const ushort* __restrict__ H,
                                                    const int* __restrict__ row_start,
                                                    const int2* __restrict__ csr2,
                                                    const float* __restrict__ dinv,
                                                    const float* __restrict__ bias,
                                                    ushort* __restrict__ Y,
                                                    float* __restrict__ bnpart, int N) {
    int g = threadIdx.x >> 6, lane = threadIdx.x & 63;
    int d = lane * 2;
    float b0 = bias[d], b1 = bias[d + 1];
    float s0 = 0.f, s1 = 0.f, ss0 = 0.f, ss1 = 0.f;

    int nchunks = (N + 3) / 4;
    int chunk = blockIdx.x * 4 + g;

    if (chunk < nchunks) {
        int c = chunk * 4;
        int nn = min(4, N - c);

        // row_start[c..c+4] via one lane-load + shfl
        int rsv = row_start[c + min(lane, nn)];
        int rs0 = __shfl(rsv, 0);
        int rs1 = __shfl(rsv, min(1, nn));
        int rs2 = __shfl(rsv, min(2, nn));
        int rs3 = __shfl(rsv, min(3, nn));
        int rs4 = __shfl(rsv, nn);

        // dinv for the 4 nodes
        float dvv = dinv[c + min(lane, nn - 1)];
        float dv0 = __shfl(dvv, 0);
        float dv1 = __shfl(dvv, min(1, nn - 1));
        float dv2 = __shfl(dvv, min(2, nn - 1));
        float dv3 = __shfl(dvv, min(3, nn - 1));

        // self rows (prefetched up front)
        uint h0 = *(const uint*)&H[(size_t)c * 128 + d];
        uint h1 = (nn > 1) ? *(const uint*)&H[(size_t)(c + 1) * 128 + d] : 0u;
        uint h2 = (nn > 2) ? *(const uint*)&H[(size_t)(c + 2) * 128 + d] : 0u;
        uint h3 = (nn > 3) ? *(const uint*)&H[(size_t)(c + 3) * 128 + d] : 0u;

        float i0_0 = bflo(h0) * dv0 * dv0 + b0, i1_0 = bfhi(h0) * dv0 * dv0 + b1;
        float i0_1 = bflo(h1) * dv1 * dv1 + b0, i1_1 = bfhi(h1) * dv1 * dv1 + b1;
        float i0_2 = bflo(h2) * dv2 * dv2 + b0, i1_2 = bfhi(h2) * dv2 * dv2 + b1;
        float i0_3 = bflo(h3) * dv3 * dv3 + b0, i1_3 = bfhi(h3) * dv3 * dv3 + b1;

        int e0 = rs0, eend = rs4;
        int seg = 0;
        int nextb = rs1;
        float a0 = i0_0, a1 = i1_0;

        for (int base = e0; base < eend; base += 64) {
            int cnt = min(64, eend - base);
            int2 me = (lane < cnt) ? csr2[base + lane] : make_int2(0, 0);
            int sl = me.x;
            float nl = __int_as_float(me.y);

            for (int j = 0; j < cnt; j += 16) {
                int mm = min(16, cnt - j);
                uint v[16]; float nr[16];
                #pragma unroll
                for (int k = 0; k < 16; ++k) {
                    int idx = min(j + k, cnt - 1);
                    int sk = __shfl(sl, idx);
                    float nk = __shfl(nl, idx);
                    nr[k] = (k < mm) ? nk : 0.f;
                    v[k] = *(const uint*)&H[(size_t)sk * 128 + d];
                }
                #pragma unroll
                for (int k = 0; k < 16; ++k) {
                    if (k < mm) {
                        int e = base + j + k;
                        while (e >= nextb) {     // uniform boundary crossing
                            float r0 = fmaxf(a0, 0.f), r1 = fmaxf(a1, 0.f);
                            *(uint*)&Y[(size_t)(c + seg) * 128 + d] =
                                (uint)f2bf(r0) | ((uint)f2bf(r1) << 16);
                            s0 += r0; ss0 += r0 * r0; s1 += r1; ss1 += r1 * r1;
                            seg++;
                            a0 = sel4f(i0_0, i0_1, i0_2, i0_3, seg);
                            a1 = sel4f(i1_0, i1_1, i1_2, i1_3, seg);
                            nextb = sel4i(rs1, rs2, rs3, rs4, seg);
                        }
                        a0 += bflo(v[k]) * nr[k];
                        a1 += bfhi(v[k]) * nr[k];
                    }
                }
            }
        }
        // final flush: current seg + trailing (possibly empty) segs
        for (;;) {
            float r0 = fmaxf(a0, 0.f), r1 = fmaxf(a1, 0.f);
            *(uint*)&Y[(size_t)(c + seg) * 128 + d] = (uint)f2bf(r0) | ((uint)f2bf(r1) << 16);
            s0 += r0; ss0 += r0 * r0; s1 += r1; ss1 += r1 * r1;
            seg++;
            if (seg >= nn) break;
            a0 = sel4f(i0_0, i0_1, i0_2, i0_3, seg);
            a1 = sel4f(i1_0, i1_1, i1_2, i1_3, seg);
            nextb = sel4i(rs1, rs2, rs3, rs4, seg);
        }
    }

    float* bp = bnpart + (size_t)(blockIdx.x & (NSLOT - 1)) * 256;   // [0..127]=sum [128..255]=ss
    __shared__ float red[4][128];
    red[g][d] = s0; red[g][d + 1] = s1;
    __syncthreads();
    if (g == 0) {
        atomicAdd(&bp[d],     red[0][d] + red[1][d] + red[2][d] + red[3][d]);
        atomicAdd(&bp[d + 1], red[0][d + 1] + red[1][d + 1] + red[2][d + 1] + red[3][d + 1]);
    }
    __syncthreads();
    red[g][d] = ss0; red[g][d + 1] = ss1;
    __syncthreads();
    if (g == 0) {
        atomicAdd(&bp[128 + d],     red[0][d] + red[1][d] + red[2][d] + red[3][d]);
        atomicAdd(&bp[128 + d + 1], red[0][d + 1] + red[1][d + 1] + red[2][d + 1] + red[3][d + 1]);
    }
}

// Sum the NSLOT partial buffers -> scale/shift; re-zero partials for the next layer.
__global__ void bnfinalize(float* __restrict__ bnpart,
                           const float* __restrict__ gamma, const float* __restrict__ beta,
                           float* __restrict__ scale, float* __restrict__ shift, float invN) {
    int d = threadIdx.x;   // 128 threads
    float sum = 0.f, ss = 0.f;
    #pragma unroll 8
    for (int s = 0; s < NSLOT; ++s) {
        sum += bnpart[s * 256 + d];
        ss  += bnpart[s * 256 + 128 + d];
        bnpart[s * 256 + d] = 0.f;
        bnpart[s * 256 + 128 + d] = 0.f;
    }
    float mu  = sum * invN;
    float var = ss * invN - mu * mu;
    float sc  = gamma[d] * rsqrtf(var + 1e-5f);
    scale[d] = sc;
    shift[d] = beta[d] - mu * sc;
}

// ---------------- Launch ----------------

static inline char* align16(char* p) { return (char*)(((uintptr_t)p + 15) & ~(uintptr_t)15); }

extern "C" void kernel_launch(void* const* d_in, const int* in_sizes, int n_in,
                              void* d_out, int out_size, void* d_ws, size_t ws_size,
                              hipStream_t stream) {
    const float* x    = (const float*)d_in[0];
    const int*   ei   = (const int*)d_in[1];
    const float* W1   = (const float*)d_in[2];
    const float* b1   = (const float*)d_in[3];
    const float* g1   = (const float*)d_in[4];
    const float* be1  = (const float*)d_in[5];
    const float* W2   = (const float*)d_in[6];
    const float* b2   = (const float*)d_in[7];
    const float* g2   = (const float*)d_in[8];
    const float* be2  = (const float*)d_in[9];
    const float* l1w  = (const float*)d_in[10];
    const float* l1b  = (const float*)d_in[11];
    const float* l2w  = (const float*)d_in[12];
    const float* l2b  = (const float*)d_in[13];
    float* out = (float*)d_out;

    int N = in_sizes[0] / 128;   // 50000
    int E = in_sizes[1] / 2;     // 640000
    const int* srcp = ei;
    const int* dstp = ei + E;

    char* w = (char*)d_ws;
    ushort* bufA  = (ushort*)w;  w = align16(w + (size_t)N * 128 * 2);
    ushort* bufB  = (ushort*)w;  w = align16(w + (size_t)N * 128 * 2);
    int*   degc   = (int*)w;     w += (size_t)N * 4;       // contiguous with bnpart (one memset)
    float* bnpart = (float*)w;   w = align16(w + (size_t)NSLOT * 256 * 4);
    float* dinv   = (float*)w;   w = align16(w + (size_t)N * 4);
    int*   row_st = (int*)w;     w = align16(w + (size_t)(N + 1) * 4);
    int*   cursor = (int*)w;     w = align16(w + (size_t)N * 4);
    int*   bsum   = (int*)w;     w = align16(w + 256 * 4);
    int2*  csr2   = (int2*)w;    w = align16(w + (size_t)E * 8);
    float* scale  = (float*)w;   w = align16(w + 128 * 4);
    float* shift  = (float*)w;   w = align16(w + 128 * 4);
    float* w2t    = (float*)w;   w = align16(w + 1280 * 4);
    ushort* wt1   = (ushort*)w;  w = align16(w + 16384 * 2);
    ushort* wt2   = (ushort*)w;  w = align16(w + 16384 * 2);
    ushort* wt3   = (ushort*)w;  w = align16(w + 16384 * 2);

    int eg = (E + 255) / 256;
    int ng = (N + 255) / 256;                // scan block count (196 <= 256)
    int gemm_grid = (N + 63) / 64;
    int nchunks = (N + 3) / 4;
    int gather_grid = (nchunks + 3) / 4;     // one chunk per wave, 4 waves/block

    // ---- CSR build + weight prep (one memset covers degc + bnpart) ----
    hipMemsetAsync(degc, 0, ((size_t)N + NSLOT * 256) * 4, stream);
    deg_count<<<eg, 256, 0, stream>>>(dstp, degc, E);
    deg_block_sum<<<ng, 256, 0, stream>>>(degc, bsum, N);
    fill_rowstart<<<ng, 256, 0, stream>>>(degc, bsum, row_st, cursor, dinv, N, E, ng);
    csr_fill<<<eg, 256, 0, stream>>>(srcp, dstp, dinv, cursor, csr2, E);
    prep_weights<<<192, 256, 0, stream>>>(W1, W2, l1w, l2w, wt1, wt2, wt3, w2t);

    // ---- layer 1 ----
    gemm_mfma<true, false, false, false, false><<<gemm_grid, 256, 0, stream>>>(
        x, nullptr, nullptr, wt1, nullptr, bufA, nullptr, nullptr, nullptr, N);
    gather_fused<<<gather_grid, 256, 0, stream>>>(bufA, row_st, csr2, dinv, b1, bufB, bnpart, N);
    bnfinalize<<<1, 128, 0, stream>>>(bnpart, g1, be1, scale, shift, 1.0f / N);

    // ---- layer 2 ----
    gemm_mfma<false, true, false, false, false><<<gemm_grid, 256, 0, stream>>>(
        bufB, scale, shift, wt2, nullptr, bufA, nullptr, nullptr, nullptr, N);
    gather_fused<<<gather_grid, 256, 0, stream>>>(bufA, row_st, csr2, dinv, b2, bufB, bnpart, N);
    bnfinalize<<<1, 128, 0, stream>>>(bnpart, g2, be2, scale, shift, 1.0f / N);

    // ---- head: lin1 GEMM + fused 10-logit log_softmax ----
    gemm_mfma<false, true, true, true, true><<<gemm_grid, 256, 0, stream>>>(
        bufB, scale, shift, wt3, l1b, nullptr, w2t, l2b, out, N);
}

// Round 9
// 329.486 us; speedup vs baseline: 1.1055x; 1.1055x over previous
//
#include <hip/hip_runtime.h>
#include <hip/hip_bf16.h>
#include <math.h>

typedef unsigned int uint;
typedef unsigned short ushort;
using f32x4 = __attribute__((ext_vector_type(4))) float;
using s16x8 = __attribute__((ext_vector_type(8))) short;

#define NSLOT 64   // replicated BN-stat buffers (de-contend epilogue atomics)

__device__ __forceinline__ float bflo(uint u) { return __uint_as_float(u << 16); }
__device__ __forceinline__ float bfhi(uint u) { return __uint_as_float(u & 0xffff0000u); }
__device__ __forceinline__ ushort f2bf(float f) {
    uint u = __float_as_uint(f);
    return (ushort)((u + 0x7fffu + ((u >> 16) & 1u)) >> 16);   // RNE
}
__device__ __forceinline__ float sel4f(float a, float b, float c, float d, int i) {
    float r = a; r = (i == 1) ? b : r; r = (i == 2) ? c : r; r = (i == 3) ? d : r; return r;
}
__device__ __forceinline__ int sel4i(int a, int b, int c, int d, int i) {
    int r = a; r = (i == 1) ? b : r; r = (i == 2) ? c : r; r = (i == 3) ? d : r; return r;
}

// ---------------- Degree / CSR ----------------

__global__ void deg_count(const int* __restrict__ dst, int* __restrict__ deg, int E) {
    int e = blockIdx.x * 256 + threadIdx.x;
    if (e < E) atomicAdd(&deg[dst[e]], 1);
}

// phase 1: per-block sum of deg
__global__ __launch_bounds__(256) void deg_block_sum(const int* __restrict__ deg,
                                                     int* __restrict__ bsum, int N) {
    __shared__ int s[256];
    int i = blockIdx.x * 256 + threadIdx.x;
    s[threadIdx.x] = (i < N) ? deg[i] : 0;
    __syncthreads();
    #pragma unroll
    for (int off = 128; off > 0; off >>= 1) {
        if (threadIdx.x < off) s[threadIdx.x] += s[threadIdx.x + off];
        __syncthreads();
    }
    if (threadIdx.x == 0) bsum[blockIdx.x] = s[0];
}

// phase 2: every block scans all block-sums in LDS (nblk<=256) + intra-block deg scan
__global__ __launch_bounds__(256) void fill_rowstart(const int* __restrict__ deg,
                                                     const int* __restrict__ bsum,
                                                     int* __restrict__ row_start,
                                                     int* __restrict__ cursor,
                                                     float* __restrict__ dinv,
                                                     int N, int E, int nblk) {
    __shared__ int s[256];
    __shared__ int sb[256];
    int t = threadIdx.x;
    int i = blockIdx.x * 256 + t;
    int dg = (i < N) ? deg[i] : 0;
    s[t] = dg;
    sb[t] = (t < nblk) ? bsum[t] : 0;
    __syncthreads();
    for (int off = 1; off < 256; off <<= 1) {
        int v1 = (t >= off) ? s[t - off] : 0;
        int v2 = (t >= off) ? sb[t - off] : 0;
        __syncthreads();
        s[t] += v1;
        sb[t] += v2;
        __syncthreads();
    }
    if (i < N) {
        int boff = (blockIdx.x == 0) ? 0 : sb[blockIdx.x - 1];
        int excl = boff + s[t] - dg;
        row_start[i] = excl;
        cursor[i] = excl;
        dinv[i] = rsqrtf((float)dg + 1.0f);
    }
    if (i == 0) row_start[N] = E;
}

__global__ void csr_fill(const int* __restrict__ src, const int* __restrict__ dst,
                         const float* __restrict__ dinv, int* __restrict__ cursor,
                         int2* __restrict__ csr2, int E) {
    int e = blockIdx.x * 256 + threadIdx.x;
    if (e >= E) return;
    int s = src[e], d = dst[e];
    int pos = atomicAdd(&cursor[d], 1);
    csr2[pos] = make_int2(s, __float_as_int(dinv[s] * dinv[d]));
}

// ---------------- Weight prep: 3x (W [k][n] f32 -> [n][k] bf16) + head W2/b2 (padded) ----------------

__global__ __launch_bounds__(256) void prep_weights(const float* __restrict__ W1,
                                                    const float* __restrict__ W2,
                                                    const float* __restrict__ W3,
                                                    const float* __restrict__ l2w,
                                                    const float* __restrict__ l2b,
                                                    ushort* __restrict__ wt1,
                                                    ushort* __restrict__ wt2,
                                                    ushort* __restrict__ wt3,
                                                    ushort* __restrict__ w2bf,
                                                    float* __restrict__ b2pad) {
    int i = blockIdx.x * 256 + threadIdx.x;      // 0..49151
    int li = i & 16383;
    int k = li >> 7, n = li & 127;
    const float* Ws = (i < 16384) ? W1 : (i < 32768) ? W2 : W3;
    ushort* Wd = (i < 16384) ? wt1 : (i < 32768) ? wt2 : wt3;
    Wd[n * 128 + k] = f2bf(Ws[li]);
    if (i < 2048) {                               // W2bf [16 classes][128 k], rows 10..15 = 0
        int c = i >> 7, kk = i & 127;
        float v = (c < 10) ? l2w[kk * 10 + c] : 0.f;
        w2bf[c * 128 + kk] = f2bf(v);
    }
    if (i < 16) b2pad[i] = (i < 10) ? l2b[i] : -1e30f;
}

// ---------------- bf16 MFMA GEMM (optionally fused MFMA-based log_softmax head) ----------------

template<bool XF32, bool AFF, bool BIAS, bool RELU, bool HEAD>
__global__ __launch_bounds__(256) void gemm_mfma(const void* __restrict__ Xv,
                                                 const float* __restrict__ scale,
                                                 const float* __restrict__ shift,
                                                 const ushort* __restrict__ Bt,
                                                 const float* __restrict__ bias,
                                                 ushort* __restrict__ Y,
                                                 const ushort* __restrict__ W2bf,
                                                 const float* __restrict__ b2pad,
                                                 float* __restrict__ OUT, int N) {
    __shared__ char smem[16384 + 32768];
    char* Al = smem;            // 64 rows x 256B, unit u at row*256 + (u^(row&7))*16
    char* Bl = smem + 16384;    // 128 n-rows x 256B, same swizzle

    int tid = threadIdx.x;
    int brow = blockIdx.x * 64;

    {
        int n = tid >> 1, h = tid & 1;
        const uint4* srcp = (const uint4*)(Bt + n * 128 + h * 64);
        #pragma unroll
        for (int i = 0; i < 8; ++i) {
            uint4 v = srcp[i];
            int u = (h * 8 + i) ^ (n & 7);
            *(uint4*)(Bl + n * 256 + u * 16) = v;
        }
    }
    {
        int r = tid >> 2, c0 = (tid & 3) * 32;
        int row = brow + r;
        bool ok = row < N;
        uint pk[16];
        if (XF32) {
            const float* Xr = (const float*)Xv + (size_t)row * 128 + c0;
            #pragma unroll
            for (int i = 0; i < 16; ++i) {
                float f0 = ok ? Xr[i * 2] : 0.f;
                float f1 = ok ? Xr[i * 2 + 1] : 0.f;
                pk[i] = (uint)f2bf(f0) | ((uint)f2bf(f1) << 16);
            }
        } else {
            const uint* Xr = (const uint*)((const ushort*)Xv + (size_t)row * 128 + c0);
            #pragma unroll
            for (int i = 0; i < 16; ++i) {
                uint u = ok ? Xr[i] : 0u;
                float f0 = bflo(u), f1 = bfhi(u);
                if (AFF) {
                    int c = c0 + i * 2;
                    f0 = f0 * scale[c] + shift[c];
                    f1 = f1 * scale[c + 1] + shift[c + 1];
                }
                pk[i] = (uint)f2bf(f0) | ((uint)f2bf(f1) << 16);
            }
        }
        #pragma unroll
        for (int i = 0; i < 4; ++i) {
            int u = ((tid & 3) * 4 + i) ^ (r & 7);
            *(uint4*)(Al + r * 256 + u * 16) = *(uint4*)&pk[i * 4];
        }
    }
    __syncthreads();

    int lane = tid & 63, w = tid >> 6;
    int m = lane & 15, g = lane >> 4;
    int wr = w * 16;

    f32x4 acc[8];
    #pragma unroll
    for (int nt = 0; nt < 8; ++nt) acc[nt] = (f32x4){0.f, 0.f, 0.f, 0.f};

    #pragma unroll
    for (int kk = 0; kk < 4; ++kk) {
        int u = (kk * 4 + g) ^ (m & 7);
        s16x8 a = *(const s16x8*)(Al + (wr + m) * 256 + u * 16);
        #pragma unroll
        for (int nt = 0; nt < 8; ++nt) {
            s16x8 b = *(const s16x8*)(Bl + (nt * 16 + m) * 256 + u * 16);
            acc[nt] = __builtin_amdgcn_mfma_f32_16x16x32_bf16(a, b, acc[nt], 0, 0, 0);
        }
    }

    float bv[8];
    if (BIAS) {
        #pragma unroll
        for (int nt = 0; nt < 8; ++nt) bv[nt] = bias[nt * 16 + m];
    }

    if (!HEAD) {
        #pragma unroll
        for (int i = 0; i < 4; ++i) {
            int row = brow + wr + g * 4 + i;
            if (row < N) {
                #pragma unroll
                for (int nt = 0; nt < 8; ++nt) {
                    float v = acc[nt][i];
                    if (BIAS) v += bv[nt];
                    if (RELU) v = fmaxf(v, 0.f);
                    Y[(size_t)row * 128 + nt * 16 + m] = f2bf(v);
                }
            }
        }
    } else {
        // Write this wave's 16 h rows (bias+relu, bf16) back into its OWN A-LDS region
        // in MFMA-A fragment layout (same XOR swizzle). Wave-private rows.
        #pragma unroll
        for (int i = 0; i < 4; ++i) {
            int r = wr + g * 4 + i;
            #pragma unroll
            for (int nt = 0; nt < 8; ++nt) {
                float v = acc[nt][i] + bv[nt];
                v = fmaxf(v, 0.f);
                int col = nt * 16 + m;
                int u = (col >> 3) ^ (r & 7);
                *(ushort*)(Al + r * 256 + u * 16 + (col & 7) * 2) = f2bf(v);
            }
        }
        __syncthreads();
        // logits[row][class] = h @ W2bf^T + b2 via one 16x16x32 MFMA chain (classes padded to 16)
        float b2v = b2pad[m];
        f32x4 lg = (f32x4){b2v, b2v, b2v, b2v};
        #pragma unroll
        for (int kk = 0; kk < 4; ++kk) {
            int u = (kk * 4 + g) ^ (m & 7);
            s16x8 a = *(const s16x8*)(Al + (wr + m) * 256 + u * 16);
            s16x8 b = *(const s16x8*)(&W2bf[m * 128 + (kk * 4 + g) * 8]);
            lg = __builtin_amdgcn_mfma_f32_16x16x32_bf16(a, b, lg, 0, 0, 0);
        }
        // C layout: class = lane&15, row = wr + g*4 + reg. log_softmax across 16 lanes/group.
        #pragma unroll
        for (int i = 0; i < 4; ++i) {
            float v = lg[i];
            float mx = v;
            #pragma unroll
            for (int off = 8; off > 0; off >>= 1) mx = fmaxf(mx, __shfl_xor(mx, off, 64));
            float ex = expf(v - mx);
            float sm = ex;
            #pragma unroll
            for (int off = 8; off > 0; off >>= 1) sm += __shfl_xor(sm, off, 64);
            float res = v - (mx + logf(sm));
            int grow = brow + wr + g * 4 + i;
            if (m < 10 && grow < N) OUT[(size_t)grow * 10 + m] = res;
        }
    }
}

// ---------------- Chunked segmented gather + self-loop + bias + ReLU + BN stats ----------------
// One wave per 4-node chunk (contiguous CSR edges). 16-deep load pipeline.
// BN stats: per-block LDS reduce -> atomics into one of NSLOT replicated buffers.

__global__ __launch_bounds__(256) void gather_fused(const ushort* __restrict__ H,
                                                    const int* __restrict__ row_start,
                                                    const int2* __restrict__ csr2,
                                                    const float* __restrict__ dinv,
                                                    const float* __restrict__ bias,
                                                    ushort* __restrict__ Y,
                                                    float* __restrict__ bnpart, int N) {
    int g = threadIdx.x >> 6, lane = threadIdx.x & 63;
    int d = lane * 2;
    float b0 = bias[d], b1 = bias[d + 1];
    float s0 = 0.f, s1 = 0.f, ss0 = 0.f, ss1 = 0.f;

    int nchunks = (N + 3) / 4;
    int chunk = blockIdx.x * 4 + g;

    if (chunk < nchunks) {
        int c = chunk * 4;
        int nn = min(4, N - c);

        // row_start[c..c+4] via one lane-load + shfl
        int rsv = row_start[c + min(lane, nn)];
        int rs0 = __shfl(rsv, 0);
        int rs1 = __shfl(rsv, min(1, nn));
        int rs2 = __shfl(rsv, min(2, nn));
        int rs3 = __shfl(rsv, min(3, nn));
        int rs4 = __shfl(rsv, nn);

        // dinv for the 4 nodes
        float dvv = dinv[c + min(lane, nn - 1)];
        float dv0 = __shfl(dvv, 0);
        float dv1 = __shfl(dvv, min(1, nn - 1));
        float dv2 = __shfl(dvv, min(2, nn - 1));
        float dv3 = __shfl(dvv, min(3, nn - 1));

        // self rows (prefetched up front)
        uint h0 = *(const uint*)&H[(size_t)c * 128 + d];
        uint h1 = (nn > 1) ? *(const uint*)&H[(size_t)(c + 1) * 128 + d] : 0u;
        uint h2 = (nn > 2) ? *(const uint*)&H[(size_t)(c + 2) * 128 + d] : 0u;
        uint h3 = (nn > 3) ? *(const uint*)&H[(size_t)(c + 3) * 128 + d] : 0u;

        float i0_0 = bflo(h0) * dv0 * dv0 + b0, i1_0 = bfhi(h0) * dv0 * dv0 + b1;
        float i0_1 = bflo(h1) * dv1 * dv1 + b0, i1_1 = bfhi(h1) * dv1 * dv1 + b1;
        float i0_2 = bflo(h2) * dv2 * dv2 + b0, i1_2 = bfhi(h2) * dv2 * dv2 + b1;
        float i0_3 = bflo(h3) * dv3 * dv3 + b0, i1_3 = bfhi(h3) * dv3 * dv3 + b1;

        int e0 = rs0, eend = rs4;
        int seg = 0;
        int nextb = rs1;
        float a0 = i0_0, a1 = i1_0;

        for (int base = e0; base < eend; base += 64) {
            int cnt = min(64, eend - base);
            int2 me = (lane < cnt) ? csr2[base + lane] : make_int2(0, 0);
            int sl = me.x;
            float nl = __int_as_float(me.y);

            for (int j = 0; j < cnt; j += 16) {
                int mm = min(16, cnt - j);
                uint v[16]; float nr[16];
                #pragma unroll
                for (int k = 0; k < 16; ++k) {
                    int idx = min(j + k, cnt - 1);
                    int sk = __shfl(sl, idx);
                    float nk = __shfl(nl, idx);
                    nr[k] = (k < mm) ? nk : 0.f;
                    v[k] = *(const uint*)&H[(size_t)sk * 128 + d];
                }
                #pragma unroll
                for (int k = 0; k < 16; ++k) {
                    if (k < mm) {
                        int e = base + j + k;
                        while (e >= nextb) {     // uniform boundary crossing
                            float r0 = fmaxf(a0, 0.f), r1 = fmaxf(a1, 0.f);
                            *(uint*)&Y[(size_t)(c + seg) * 128 + d] =
                                (uint)f2bf(r0) | ((uint)f2bf(r1) << 16);
                            s0 += r0; ss0 += r0 * r0; s1 += r1; ss1 += r1 * r1;
                            seg++;
                            a0 = sel4f(i0_0, i0_1, i0_2, i0_3, seg);
                            a1 = sel4f(i1_0, i1_1, i1_2, i1_3, seg);
                            nextb = sel4i(rs1, rs2, rs3, rs4, seg);
                        }
                        a0 += bflo(v[k]) * nr[k];
                        a1 += bfhi(v[k]) * nr[k];
                    }
                }
            }
        }
        // final flush: current seg + trailing (possibly empty) segs
        for (;;) {
            float r0 = fmaxf(a0, 0.f), r1 = fmaxf(a1, 0.f);
            *(uint*)&Y[(size_t)(c + seg) * 128 + d] = (uint)f2bf(r0) | ((uint)f2bf(r1) << 16);
            s0 += r0; ss0 += r0 * r0; s1 += r1; ss1 += r1 * r1;
            seg++;
            if (seg >= nn) break;
            a0 = sel4f(i0_0, i0_1, i0_2, i0_3, seg);
            a1 = sel4f(i1_0, i1_1, i1_2, i1_3, seg);
            nextb = sel4i(rs1, rs2, rs3, rs4, seg);
        }
    }

    float* bp = bnpart + (size_t)(blockIdx.x & (NSLOT - 1)) * 256;   // [0..127]=sum [128..255]=ss
    __shared__ float red[4][128];
    red[g][d] = s0; red[g][d + 1] = s1;
    __syncthreads();
    if (g == 0) {
        atomicAdd(&bp[d],     red[0][d] + red[1][d] + red[2][d] + red[3][d]);
        atomicAdd(&bp[d + 1], red[0][d + 1] + red[1][d + 1] + red[2][d + 1] + red[3][d + 1]);
    }
    __syncthreads();
    red[g][d] = ss0; red[g][d + 1] = ss1;
    __syncthreads();
    if (g == 0) {
        atomicAdd(&bp[128 + d],     red[0][d] + red[1][d] + red[2][d] + red[3][d]);
        atomicAdd(&bp[128 + d + 1], red[0][d + 1] + red[1][d + 1] + red[2][d + 1] + red[3][d + 1]);
    }
}

// Sum the NSLOT partial buffers -> scale/shift; re-zero partials for the next layer.
__global__ void bnfinalize(float* __restrict__ bnpart,
                           const float* __restrict__ gamma, const float* __restrict__ beta,
                           float* __restrict__ scale, float* __restrict__ shift, float invN) {
    int d = threadIdx.x;   // 128 threads
    float sum = 0.f, ss = 0.f;
    #pragma unroll 8
    for (int s = 0; s < NSLOT; ++s) {
        sum += bnpart[s * 256 + d];
        ss  += bnpart[s * 256 + 128 + d];
        bnpart[s * 256 + d] = 0.f;
        bnpart[s * 256 + 128 + d] = 0.f;
    }
    float mu  = sum * invN;
    float var = ss * invN - mu * mu;
    float sc  = gamma[d] * rsqrtf(var + 1e-5f);
    scale[d] = sc;
    shift[d] = beta[d] - mu * sc;
}

// ---------------- Launch ----------------

static inline char* align16(char* p) { return (char*)(((uintptr_t)p + 15) & ~(uintptr_t)15); }

extern "C" void kernel_launch(void* const* d_in, const int* in_sizes, int n_in,
                              void* d_out, int out_size, void* d_ws, size_t ws_size,
                              hipStream_t stream) {
    const float* x    = (const float*)d_in[0];
    const int*   ei   = (const int*)d_in[1];
    const float* W1   = (const float*)d_in[2];
    const float* b1   = (const float*)d_in[3];
    const float* g1   = (const float*)d_in[4];
    const float* be1  = (const float*)d_in[5];
    const float* W2   = (const float*)d_in[6];
    const float* b2   = (const float*)d_in[7];
    const float* g2   = (const float*)d_in[8];
    const float* be2  = (const float*)d_in[9];
    const float* l1w  = (const float*)d_in[10];
    const float* l1b  = (const float*)d_in[11];
    const float* l2w  = (const float*)d_in[12];
    const float* l2b  = (const float*)d_in[13];
    float* out = (float*)d_out;

    int N = in_sizes[0] / 128;   // 50000
    int E = in_sizes[1] / 2;     // 640000
    const int* srcp = ei;
    const int* dstp = ei + E;

    char* w = (char*)d_ws;
    ushort* bufA  = (ushort*)w;  w = align16(w + (size_t)N * 128 * 2);
    ushort* bufB  = (ushort*)w;  w = align16(w + (size_t)N * 128 * 2);
    int*   degc   = (int*)w;     w += (size_t)N * 4;       // contiguous with bnpart (one memset)
    float* bnpart = (float*)w;   w = align16(w + (size_t)NSLOT * 256 * 4);
    float* dinv   = (float*)w;   w = align16(w + (size_t)N * 4);
    int*   row_st = (int*)w;     w = align16(w + (size_t)(N + 1) * 4);
    int*   cursor = (int*)w;     w = align16(w + (size_t)N * 4);
    int*   bsum   = (int*)w;     w = align16(w + 256 * 4);
    int2*  csr2   = (int2*)w;    w = align16(w + (size_t)E * 8);
    float* scale  = (float*)w;   w = align16(w + 128 * 4);
    float* shift  = (float*)w;   w = align16(w + 128 * 4);
    ushort* wt1   = (ushort*)w;  w = align16(w + 16384 * 2);
    ushort* wt2   = (ushort*)w;  w = align16(w + 16384 * 2);
    ushort* wt3   = (ushort*)w;  w = align16(w + 16384 * 2);
    ushort* w2bf  = (ushort*)w;  w = align16(w + 2048 * 2);
    float* b2pad  = (float*)w;   w = align16(w + 16 * 4);

    int eg = (E + 255) / 256;
    int ng = (N + 255) / 256;                // scan block count (196 <= 256)
    int gemm_grid = (N + 63) / 64;
    int nchunks = (N + 3) / 4;
    int gather_grid = (nchunks + 3) / 4;     // one chunk per wave, 4 waves/block

    // ---- CSR build + weight prep (one memset covers degc + bnpart) ----
    hipMemsetAsync(degc, 0, ((size_t)N + NSLOT * 256) * 4, stream);
    deg_count<<<eg, 256, 0, stream>>>(dstp, degc, E);
    deg_block_sum<<<ng, 256, 0, stream>>>(degc, bsum, N);
    fill_rowstart<<<ng, 256, 0, stream>>>(degc, bsum, row_st, cursor, dinv, N, E, ng);
    csr_fill<<<eg, 256, 0, stream>>>(srcp, dstp, dinv, cursor, csr2, E);
    prep_weights<<<192, 256, 0, stream>>>(W1, W2, l1w, l2w, l2b, wt1, wt2, wt3, w2bf, b2pad);

    // ---- layer 1 ----
    gemm_mfma<true, false, false, false, false><<<gemm_grid, 256, 0, stream>>>(
        x, nullptr, nullptr, wt1, nullptr, bufA, nullptr, nullptr, nullptr, N);
    gather_fused<<<gather_grid, 256, 0, stream>>>(bufA, row_st, csr2, dinv, b1, bufB, bnpart, N);
    bnfinalize<<<1, 128, 0, stream>>>(bnpart, g1, be1, scale, shift, 1.0f / N);

    // ---- layer 2 ----
    gemm_mfma<false, true, false, false, false><<<gemm_grid, 256, 0, stream>>>(
        bufB, scale, shift, wt2, nullptr, bufA, nullptr, nullptr, nullptr, N);
    gather_fused<<<gather_grid, 256, 0, stream>>>(bufA, row_st, csr2, dinv, b2, bufB, bnpart, N);
    bnfinalize<<<1, 128, 0, stream>>>(bnpart, g2, be2, scale, shift, 1.0f / N);

    // ---- head: lin1 GEMM + MFMA logits + lane-tree log_softmax ----
    gemm_mfma<false, true, true, true, true><<<gemm_grid, 256, 0, stream>>>(
        bufB, scale, shift, wt3, l1b, nullptr, w2bf, b2pad, out, N);
}

// Round 10
// 323.257 us; speedup vs baseline: 1.1268x; 1.0193x over previous
//
#include <hip/hip_runtime.h>
#include <hip/hip_bf16.h>
#include <math.h>

typedef unsigned int uint;
typedef unsigned short ushort;
using f32x4 = __attribute__((ext_vector_type(4))) float;
using s16x8 = __attribute__((ext_vector_type(8))) short;

#define NSLOT 64   // replicated BN-stat buffers (de-contend epilogue atomics)

__device__ __forceinline__ float bflo(uint u) { return __uint_as_float(u << 16); }
__device__ __forceinline__ float bfhi(uint u) { return __uint_as_float(u & 0xffff0000u); }
__device__ __forceinline__ ushort f2bf(float f) {
    uint u = __float_as_uint(f);
    return (ushort)((u + 0x7fffu + ((u >> 16) & 1u)) >> 16);   // RNE
}
__device__ __forceinline__ float sel4f(float a, float b, float c, float d, int i) {
    float r = a; r = (i == 1) ? b : r; r = (i == 2) ? c : r; r = (i == 3) ? d : r; return r;
}
__device__ __forceinline__ int sel4i(int a, int b, int c, int d, int i) {
    int r = a; r = (i == 1) ? b : r; r = (i == 2) ? c : r; r = (i == 3) ? d : r; return r;
}

// ---------------- Degree / CSR ----------------

__global__ void deg_count(const int* __restrict__ dst, int* __restrict__ deg, int E) {
    int e0 = blockIdx.x * 512 + threadIdx.x;
    int e1 = e0 + 256;
    if (e1 < E) {
        int dA = dst[e0], dB = dst[e1];
        atomicAdd(&deg[dA], 1);
        atomicAdd(&deg[dB], 1);
    } else if (e0 < E) {
        atomicAdd(&deg[dst[e0]], 1);
    }
}

// phase 1: per-block sum of deg
__global__ __launch_bounds__(256) void deg_block_sum(const int* __restrict__ deg,
                                                     int* __restrict__ bsum, int N) {
    __shared__ int s[256];
    int i = blockIdx.x * 256 + threadIdx.x;
    s[threadIdx.x] = (i < N) ? deg[i] : 0;
    __syncthreads();
    #pragma unroll
    for (int off = 128; off > 0; off >>= 1) {
        if (threadIdx.x < off) s[threadIdx.x] += s[threadIdx.x + off];
        __syncthreads();
    }
    if (threadIdx.x == 0) bsum[blockIdx.x] = s[0];
}

// phase 2: every block scans all block-sums in LDS (nblk<=256) + intra-block deg scan
__global__ __launch_bounds__(256) void fill_rowstart(const int* __restrict__ deg,
                                                     const int* __restrict__ bsum,
                                                     int* __restrict__ row_start,
                                                     int* __restrict__ cursor,
                                                     float* __restrict__ dinv,
                                                     int N, int E, int nblk) {
    __shared__ int s[256];
    __shared__ int sb[256];
    int t = threadIdx.x;
    int i = blockIdx.x * 256 + t;
    int dg = (i < N) ? deg[i] : 0;
    s[t] = dg;
    sb[t] = (t < nblk) ? bsum[t] : 0;
    __syncthreads();
    for (int off = 1; off < 256; off <<= 1) {
        int v1 = (t >= off) ? s[t - off] : 0;
        int v2 = (t >= off) ? sb[t - off] : 0;
        __syncthreads();
        s[t] += v1;
        sb[t] += v2;
        __syncthreads();
    }
    if (i < N) {
        int boff = (blockIdx.x == 0) ? 0 : sb[blockIdx.x - 1];
        int excl = boff + s[t] - dg;
        row_start[i] = excl;
        cursor[i] = excl;
        dinv[i] = rsqrtf((float)dg + 1.0f);
    }
    if (i == 0) row_start[N] = E;
}

// src-only CSR fill (norm factored out: GEMM pre-scales rows by dinv, gather applies dv per node)
__global__ void csr_fill(const int* __restrict__ src, const int* __restrict__ dst,
                         int* __restrict__ cursor, int* __restrict__ csr_src, int E) {
    int e0 = blockIdx.x * 512 + threadIdx.x;
    int e1 = e0 + 256;
    if (e1 < E) {
        int sA = src[e0], dA = dst[e0];
        int sB = src[e1], dB = dst[e1];
        int pA = atomicAdd(&cursor[dA], 1);
        int pB = atomicAdd(&cursor[dB], 1);
        csr_src[pA] = sA;
        csr_src[pB] = sB;
    } else if (e0 < E) {
        int s = src[e0], d = dst[e0];
        int p = atomicAdd(&cursor[d], 1);
        csr_src[p] = s;
    }
}

// ---------------- Weight prep: 3x (W [k][n] f32 -> [n][k] bf16) + head W2/b2 (padded) ----------------

__global__ __launch_bounds__(256) void prep_weights(const float* __restrict__ W1,
                                                    const float* __restrict__ W2,
                                                    const float* __restrict__ W3,
                                                    const float* __restrict__ l2w,
                                                    const float* __restrict__ l2b,
                                                    ushort* __restrict__ wt1,
                                                    ushort* __restrict__ wt2,
                                                    ushort* __restrict__ wt3,
                                                    ushort* __restrict__ w2bf,
                                                    float* __restrict__ b2pad) {
    int i = blockIdx.x * 256 + threadIdx.x;      // 0..49151
    int li = i & 16383;
    int k = li >> 7, n = li & 127;
    const float* Ws = (i < 16384) ? W1 : (i < 32768) ? W2 : W3;
    ushort* Wd = (i < 16384) ? wt1 : (i < 32768) ? wt2 : wt3;
    Wd[n * 128 + k] = f2bf(Ws[li]);
    if (i < 2048) {                               // W2bf [16 classes][128 k], rows 10..15 = 0
        int c = i >> 7, kk = i & 127;
        float v = (c < 10) ? l2w[kk * 10 + c] : 0.f;
        w2bf[c * 128 + kk] = f2bf(v);
    }
    if (i < 16) b2pad[i] = (i < 10) ? l2b[i] : -1e30f;
}

// ---------------- bf16 MFMA GEMM: 128 rows/block, dbuf A staging, B staged once ----------------
// PRESCALE: epilogue multiplies row by dinv[row] (GCN norm factoring).
// HEAD: fused 10-class logits via second MFMA + 16-lane-tree log_softmax.

template<bool XF32, bool AFF, bool PRESCALE, bool HEAD>
__global__ __launch_bounds__(256) void gemm_mfma(const void* __restrict__ Xv,
                                                 const float* __restrict__ scale,
                                                 const float* __restrict__ shift,
                                                 const ushort* __restrict__ Bt,
                                                 const float* __restrict__ bias,
                                                 const float* __restrict__ dinv,
                                                 ushort* __restrict__ Y,
                                                 const ushort* __restrict__ W2bf,
                                                 const float* __restrict__ b2pad,
                                                 float* __restrict__ OUT, int N) {
    __shared__ char smem[2 * 16384 + 32768];
    char* Bl = smem + 32768;    // 128 n-rows x 256B, swizzled: unit u at n*256 + (u^(n&7))*16

    int tid = threadIdx.x;
    int brow = blockIdx.x * 128;

    // stage B (once)
    {
        int n = tid >> 1, h = tid & 1;
        const uint4* srcp = (const uint4*)(Bt + n * 128 + h * 64);
        #pragma unroll
        for (int i = 0; i < 8; ++i) {
            uint4 v = srcp[i];
            int u = (h * 8 + i) ^ (n & 7);
            *(uint4*)(Bl + n * 256 + u * 16) = v;
        }
    }

    int lane = tid & 63, w = tid >> 6;
    int m = lane & 15, g = lane >> 4;
    int wr = w * 16;

    #pragma unroll
    for (int t = 0; t < 2; ++t) {
        char* Al = smem + t * 16384;    // 64 rows x 256B, swizzled
        int rbase = brow + t * 64;

        // stage A tile t
        {
            int r = tid >> 2, c0 = (tid & 3) * 32;
            int row = rbase + r;
            bool ok = row < N;
            uint pk[16];
            if (XF32) {
                const float* Xr = (const float*)Xv + (size_t)row * 128 + c0;
                #pragma unroll
                for (int i = 0; i < 16; ++i) {
                    float f0 = ok ? Xr[i * 2] : 0.f;
                    float f1 = ok ? Xr[i * 2 + 1] : 0.f;
                    pk[i] = (uint)f2bf(f0) | ((uint)f2bf(f1) << 16);
                }
            } else {
                const uint* Xr = (const uint*)((const ushort*)Xv + (size_t)row * 128 + c0);
                #pragma unroll
                for (int i = 0; i < 16; ++i) {
                    uint u = ok ? Xr[i] : 0u;
                    float f0 = bflo(u), f1 = bfhi(u);
                    if (AFF) {
                        int c = c0 + i * 2;
                        f0 = f0 * scale[c] + shift[c];
                        f1 = f1 * scale[c + 1] + shift[c + 1];
                    }
                    pk[i] = (uint)f2bf(f0) | ((uint)f2bf(f1) << 16);
                }
            }
            #pragma unroll
            for (int i = 0; i < 4; ++i) {
                int u = ((tid & 3) * 4 + i) ^ (r & 7);
                *(uint4*)(Al + r * 256 + u * 16) = *(uint4*)&pk[i * 4];
            }
        }
        __syncthreads();

        f32x4 acc[8];
        #pragma unroll
        for (int nt = 0; nt < 8; ++nt) acc[nt] = (f32x4){0.f, 0.f, 0.f, 0.f};

        #pragma unroll
        for (int kk = 0; kk < 4; ++kk) {
            int u = (kk * 4 + g) ^ (m & 7);
            s16x8 a = *(const s16x8*)(Al + (wr + m) * 256 + u * 16);
            #pragma unroll
            for (int nt = 0; nt < 8; ++nt) {
                s16x8 b = *(const s16x8*)(Bl + (nt * 16 + m) * 256 + u * 16);
                acc[nt] = __builtin_amdgcn_mfma_f32_16x16x32_bf16(a, b, acc[nt], 0, 0, 0);
            }
        }

        if (!HEAD) {
            #pragma unroll
            for (int i = 0; i < 4; ++i) {
                int row = rbase + wr + g * 4 + i;
                if (row < N) {
                    float dv = PRESCALE ? dinv[row] : 1.f;
                    #pragma unroll
                    for (int nt = 0; nt < 8; ++nt) {
                        float v = acc[nt][i];
                        if (PRESCALE) v *= dv;
                        Y[(size_t)row * 128 + nt * 16 + m] = f2bf(v);
                    }
                }
            }
        } else {
            float bv[8];
            #pragma unroll
            for (int nt = 0; nt < 8; ++nt) bv[nt] = bias[nt * 16 + m];
            // write this wave's 16 h rows (bias+relu, bf16) into its OWN A-LDS rows (frag layout)
            #pragma unroll
            for (int i = 0; i < 4; ++i) {
                int r = wr + g * 4 + i;
                #pragma unroll
                for (int nt = 0; nt < 8; ++nt) {
                    float v = fmaxf(acc[nt][i] + bv[nt], 0.f);
                    int col = nt * 16 + m;
                    int u = (col >> 3) ^ (r & 7);
                    *(ushort*)(Al + r * 256 + u * 16 + (col & 7) * 2) = f2bf(v);
                }
            }
            __syncthreads();
            float b2v = b2pad[m];
            f32x4 lg = (f32x4){b2v, b2v, b2v, b2v};
            #pragma unroll
            for (int kk = 0; kk < 4; ++kk) {
                int u = (kk * 4 + g) ^ (m & 7);
                s16x8 a = *(const s16x8*)(Al + (wr + m) * 256 + u * 16);
                s16x8 b = *(const s16x8*)(&W2bf[m * 128 + (kk * 4 + g) * 8]);
                lg = __builtin_amdgcn_mfma_f32_16x16x32_bf16(a, b, lg, 0, 0, 0);
            }
            #pragma unroll
            for (int i = 0; i < 4; ++i) {
                float v = lg[i];
                float mx = v;
                #pragma unroll
                for (int off = 8; off > 0; off >>= 1) mx = fmaxf(mx, __shfl_xor(mx, off, 64));
                float ex = expf(v - mx);
                float sm = ex;
                #pragma unroll
                for (int off = 8; off > 0; off >>= 1) sm += __shfl_xor(sm, off, 64);
                float res = v - (mx + logf(sm));
                int grow = rbase + wr + g * 4 + i;
                if (m < 10 && grow < N) OUT[(size_t)grow * 10 + m] = res;
            }
        }
    }
}

// ---------------- Chunked segmented gather (pre-scaled H) + self-loop + bias + ReLU + BN stats ----
// Edge contribution = H'[s]; segment sum multiplied by dv(dst) at boundary. Pure adds per edge.

__global__ __launch_bounds__(256) void gather_fused(const ushort* __restrict__ H,
                                                    const int* __restrict__ row_start,
                                                    const int* __restrict__ csr_src,
                                                    const float* __restrict__ dinv,
                                                    const float* __restrict__ bias,
                                                    ushort* __restrict__ Y,
                                                    float* __restrict__ bnpart, int N) {
    int g = threadIdx.x >> 6, lane = threadIdx.x & 63;
    int d = lane * 2;
    float b0 = bias[d], b1 = bias[d + 1];
    float s0 = 0.f, s1 = 0.f, ss0 = 0.f, ss1 = 0.f;

    int nchunks = (N + 3) / 4;
    int chunk = blockIdx.x * 4 + g;

    if (chunk < nchunks) {
        int c = chunk * 4;
        int nn = min(4, N - c);

        int rsv = row_start[c + min(lane, nn)];
        int rs0 = __shfl(rsv, 0);
        int rs1 = __shfl(rsv, min(1, nn));
        int rs2 = __shfl(rsv, min(2, nn));
        int rs3 = __shfl(rsv, min(3, nn));
        int rs4 = __shfl(rsv, nn);

        float dvv = dinv[c + min(lane, nn - 1)];
        float dv0 = __shfl(dvv, 0);
        float dv1 = __shfl(dvv, min(1, nn - 1));
        float dv2 = __shfl(dvv, min(2, nn - 1));
        float dv3 = __shfl(dvv, min(3, nn - 1));

        // self rows (H is pre-scaled by dinv): self contribution = H'[n]*dv
        uint h0 = *(const uint*)&H[(size_t)c * 128 + d];
        uint h1 = (nn > 1) ? *(const uint*)&H[(size_t)(c + 1) * 128 + d] : 0u;
        uint h2 = (nn > 2) ? *(const uint*)&H[(size_t)(c + 2) * 128 + d] : 0u;
        uint h3 = (nn > 3) ? *(const uint*)&H[(size_t)(c + 3) * 128 + d] : 0u;

        float i0_0 = bflo(h0) * dv0 + b0, i1_0 = bfhi(h0) * dv0 + b1;
        float i0_1 = bflo(h1) * dv1 + b0, i1_1 = bfhi(h1) * dv1 + b1;
        float i0_2 = bflo(h2) * dv2 + b0, i1_2 = bfhi(h2) * dv2 + b1;
        float i0_3 = bflo(h3) * dv3 + b0, i1_3 = bfhi(h3) * dv3 + b1;

        int e0 = rs0, eend = rs4;
        int seg = 0;
        int nextb = rs1;
        float i0s = i0_0, i1s = i1_0, dvs = dv0;
        float es0 = 0.f, es1 = 0.f;

        for (int base = e0; base < eend; base += 64) {
            int cnt = min(64, eend - base);
            int sl = (lane < cnt) ? csr_src[base + lane] : 0;

            for (int j = 0; j < cnt; j += 16) {
                int mm = min(16, cnt - j);
                uint v[16];
                #pragma unroll
                for (int k = 0; k < 16; ++k) {
                    int idx = min(j + k, cnt - 1);
                    int sk = __shfl(sl, idx);
                    v[k] = *(const uint*)&H[(size_t)sk * 128 + d];
                }
                #pragma unroll
                for (int k = 0; k < 16; ++k) {
                    if (k < mm) {
                        int e = base + j + k;
                        while (e >= nextb) {     // uniform boundary crossing
                            float r0 = fmaxf(es0 * dvs + i0s, 0.f);
                            float r1 = fmaxf(es1 * dvs + i1s, 0.f);
                            *(uint*)&Y[(size_t)(c + seg) * 128 + d] =
                                (uint)f2bf(r0) | ((uint)f2bf(r1) << 16);
                            s0 += r0; ss0 += r0 * r0; s1 += r1; ss1 += r1 * r1;
                            seg++;
                            i0s = sel4f(i0_0, i0_1, i0_2, i0_3, seg);
                            i1s = sel4f(i1_0, i1_1, i1_2, i1_3, seg);
                            dvs = sel4f(dv0, dv1, dv2, dv3, seg);
                            nextb = sel4i(rs1, rs2, rs3, rs4, seg);
                            es0 = 0.f; es1 = 0.f;
                        }
                        es0 += bflo(v[k]);
                        es1 += bfhi(v[k]);
                    }
                }
            }
        }
        // final flush: current seg + trailing (possibly empty) segs
        for (;;) {
            float r0 = fmaxf(es0 * dvs + i0s, 0.f);
            float r1 = fmaxf(es1 * dvs + i1s, 0.f);
            *(uint*)&Y[(size_t)(c + seg) * 128 + d] = (uint)f2bf(r0) | ((uint)f2bf(r1) << 16);
            s0 += r0; ss0 += r0 * r0; s1 += r1; ss1 += r1 * r1;
            seg++;
            if (seg >= nn) break;
            i0s = sel4f(i0_0, i0_1, i0_2, i0_3, seg);
            i1s = sel4f(i1_0, i1_1, i1_2, i1_3, seg);
            dvs = sel4f(dv0, dv1, dv2, dv3, seg);
            nextb = sel4i(rs1, rs2, rs3, rs4, seg);
            es0 = 0.f; es1 = 0.f;
        }
    }

    float* bp = bnpart + (size_t)(blockIdx.x & (NSLOT - 1)) * 256;   // [0..127]=sum [128..255]=ss
    __shared__ float red[4][128];
    red[g][d] = s0; red[g][d + 1] = s1;
    __syncthreads();
    if (g == 0) {
        atomicAdd(&bp[d],     red[0][d] + red[1][d] + red[2][d] + red[3][d]);
        atomicAdd(&bp[d + 1], red[0][d + 1] + red[1][d + 1] + red[2][d + 1] + red[3][d + 1]);
    }
    __syncthreads();
    red[g][d] = ss0; red[g][d + 1] = ss1;
    __syncthreads();
    if (g == 0) {
        atomicAdd(&bp[128 + d],     red[0][d] + red[1][d] + red[2][d] + red[3][d]);
        atomicAdd(&bp[128 + d + 1], red[0][d + 1] + red[1][d + 1] + red[2][d + 1] + red[3][d + 1]);
    }
}

// Sum the NSLOT partial buffers -> scale/shift; re-zero partials for the next layer.
__global__ void bnfinalize(float* __restrict__ bnpart,
                           const float* __restrict__ gamma, const float* __restrict__ beta,
                           float* __restrict__ scale, float* __restrict__ shift, float invN) {
    int d = threadIdx.x;   // 128 threads
    float sum = 0.f, ss = 0.f;
    #pragma unroll 8
    for (int s = 0; s < NSLOT; ++s) {
        sum += bnpart[s * 256 + d];
        ss  += bnpart[s * 256 + 128 + d];
        bnpart[s * 256 + d] = 0.f;
        bnpart[s * 256 + 128 + d] = 0.f;
    }
    float mu  = sum * invN;
    float var = ss * invN - mu * mu;
    float sc  = gamma[d] * rsqrtf(var + 1e-5f);
    scale[d] = sc;
    shift[d] = beta[d] - mu * sc;
}

// ---------------- Launch ----------------

static inline char* align16(char* p) { return (char*)(((uintptr_t)p + 15) & ~(uintptr_t)15); }

extern "C" void kernel_launch(void* const* d_in, const int* in_sizes, int n_in,
                              void* d_out, int out_size, void* d_ws, size_t ws_size,
                              hipStream_t stream) {
    const float* x    = (const float*)d_in[0];
    const int*   ei   = (const int*)d_in[1];
    const float* W1   = (const float*)d_in[2];
    const float* b1   = (const float*)d_in[3];
    const float* g1   = (const float*)d_in[4];
    const float* be1  = (const float*)d_in[5];
    const float* W2   = (const float*)d_in[6];
    const float* b2   = (const float*)d_in[7];
    const float* g2   = (const float*)d_in[8];
    const float* be2  = (const float*)d_in[9];
    const float* l1w  = (const float*)d_in[10];
    const float* l1b  = (const float*)d_in[11];
    const float* l2w  = (const float*)d_in[12];
    const float* l2b  = (const float*)d_in[13];
    float* out = (float*)d_out;

    int N = in_sizes[0] / 128;   // 50000
    int E = in_sizes[1] / 2;     // 640000
    const int* srcp = ei;
    const int* dstp = ei + E;

    char* w = (char*)d_ws;
    ushort* bufA   = (ushort*)w;  w = align16(w + (size_t)N * 128 * 2);
    ushort* bufB   = (ushort*)w;  w = align16(w + (size_t)N * 128 * 2);
    int*   degc    = (int*)w;     w += (size_t)N * 4;       // contiguous with bnpart (one memset)
    float* bnpart  = (float*)w;   w = align16(w + (size_t)NSLOT * 256 * 4);
    float* dinv    = (float*)w;   w = align16(w + (size_t)N * 4);
    int*   row_st  = (int*)w;     w = align16(w + (size_t)(N + 1) * 4);
    int*   cursor  = (int*)w;     w = align16(w + (size_t)N * 4);
    int*   bsum    = (int*)w;     w = align16(w + 256 * 4);
    int*   csr_src = (int*)w;     w = align16(w + (size_t)E * 4);
    float* scale   = (float*)w;   w = align16(w + 128 * 4);
    float* shift   = (float*)w;   w = align16(w + 128 * 4);
    ushort* wt1    = (ushort*)w;  w = align16(w + 16384 * 2);
    ushort* wt2    = (ushort*)w;  w = align16(w + 16384 * 2);
    ushort* wt3    = (ushort*)w;  w = align16(w + 16384 * 2);
    ushort* w2bf   = (ushort*)w;  w = align16(w + 2048 * 2);
    float* b2pad   = (float*)w;   w = align16(w + 16 * 4);

    int eg2 = (E + 511) / 512;
    int ng = (N + 255) / 256;                // scan block count (196 <= 256)
    int gemm_grid = (N + 127) / 128;         // 391
    int nchunks = (N + 3) / 4;
    int gather_grid = (nchunks + 3) / 4;     // one chunk per wave, 4 waves/block

    // ---- CSR build + weight prep (one memset covers degc + bnpart) ----
    hipMemsetAsync(degc, 0, ((size_t)N + NSLOT * 256) * 4, stream);
    deg_count<<<eg2, 256, 0, stream>>>(dstp, degc, E);
    deg_block_sum<<<ng, 256, 0, stream>>>(degc, bsum, N);
    fill_rowstart<<<ng, 256, 0, stream>>>(degc, bsum, row_st, cursor, dinv, N, E, ng);
    csr_fill<<<eg2, 256, 0, stream>>>(srcp, dstp, cursor, csr_src, E);
    prep_weights<<<192, 256, 0, stream>>>(W1, W2, l1w, l2w, l2b, wt1, wt2, wt3, w2bf, b2pad);

    // ---- layer 1 ----
    gemm_mfma<true, false, true, false><<<gemm_grid, 256, 0, stream>>>(
        x, nullptr, nullptr, wt1, nullptr, dinv, bufA, nullptr, nullptr, nullptr, N);
    gather_fused<<<gather_grid, 256, 0, stream>>>(bufA, row_st, csr_src, dinv, b1, bufB, bnpart, N);
    bnfinalize<<<1, 128, 0, stream>>>(bnpart, g1, be1, scale, shift, 1.0f / N);

    // ---- layer 2 ----
    gemm_mfma<false, true, true, false><<<gemm_grid, 256, 0, stream>>>(
        bufB, scale, shift, wt2, nullptr, dinv, bufA, nullptr, nullptr, nullptr, N);
    gather_fused<<<gather_grid, 256, 0, stream>>>(bufA, row_st, csr_src, dinv, b2, bufB, bnpart, N);
    bnfinalize<<<1, 128, 0, stream>>>(bnpart, g2, be2, scale, shift, 1.0f / N);

    // ---- head: lin1 GEMM + MFMA logits + lane-tree log_softmax ----
    gemm_mfma<false, true, false, true><<<gemm_grid, 256, 0, stream>>>(
        bufB, scale, shift, wt3, l1b, nullptr, nullptr, w2bf, b2pad, out, N);
}